// Round 3
// baseline (131080.627 us; speedup 1.0000x reference)
//
#include <hip/hip_runtime.h>
#include <cfloat>
#include <cmath>

namespace {

constexpr int Bn = 64;     // batch
constexpr int Sn = 128;    // encoder seq len
constexpr int En = 512;    // embedding dim
constexpr int Hn = 1024;   // hidden dim
constexpr int Vn = 10000;  // vocab
constexpr int Tn = 144;    // 1 + STEPS output positions
constexpr int DEC = 143;   // decode steps
constexpr int ENC_CHUNK = 16;

// ---- ws layout (units: doubles) ----
constexpr size_t BH = (size_t)Hn * 64;                 // 65536
constexpr size_t OFF_H0A = 0;
constexpr size_t OFF_H0B = BH;
constexpr size_t OFF_C0  = 2 * BH;
constexpr size_t OFF_H1A = 3 * BH;
constexpr size_t OFF_H1B = 4 * BH;
constexpr size_t OFF_C1  = 5 * BH;
constexpr size_t OFF_XT  = 6 * BH;                     // ENC_CHUNK*En*64 = 524288
constexpr size_t OFF_BC0 = OFF_XT + (size_t)ENC_CHUNK * En * 64;
constexpr size_t OFF_BC1 = OFF_BC0 + 4 * Hn;
constexpr size_t OFF_BFC = OFF_BC1 + 4 * Hn;
constexpr size_t OFF_W   = OFF_BFC + 10240;            // 935936
constexpr size_t N_WIH0  = (size_t)4 * Hn * En;        // 2,097,152
constexpr size_t N_WHH   = (size_t)4 * Hn * Hn;        // 4,194,304
constexpr size_t N_WFC   = (size_t)Vn * Hn;            // 10,240,000
constexpr size_t OFF_WIH0 = OFF_W;
constexpr size_t OFF_WHH0 = OFF_WIH0 + N_WIH0;
constexpr size_t OFF_WIH1 = OFF_WHH0 + N_WHH;
constexpr size_t OFF_WHH1 = OFF_WIH1 + N_WHH;
constexpr size_t OFF_WFC  = OFF_WHH1 + N_WHH;
constexpr size_t WS_NEED  = OFF_WFC + N_WFC;           // 25,856,000 doubles ~ 207 MB

__device__ __forceinline__ double sigd(double x) { return 1.0 / (1.0 + exp(-x)); }

// ---------- prep ----------
__global__ __launch_bounds__(256) void init_state(double* __restrict__ ws) {
    const size_t i = (size_t)blockIdx.x * blockDim.x + threadIdx.x;  // 0 .. 6*BH-1
    ws[i] = 0.0;
}

__global__ __launch_bounds__(256) void cvt_f32_f64(
    const float* __restrict__ s, double* __restrict__ d, const int n) {
    const int stride = (int)gridDim.x * 256;
    for (int i = (int)blockIdx.x * 256 + (int)threadIdx.x; i < n; i += stride)
        d[i] = (double)s[i];
}

__global__ __launch_bounds__(256) void bias_combine(
    const float* __restrict__ a, const float* __restrict__ b,
    double* __restrict__ d, const int n) {
    const int stride = (int)gridDim.x * 256;
    for (int i = (int)blockIdx.x * 256 + (int)threadIdx.x; i < n; i += stride)
        d[i] = (double)a[i] + (double)b[i];
}

// Gather ENC_CHUNK encoder embeddings into transposed f64 x_t[ti][k][b].
__global__ __launch_bounds__(256) void gather_enc(
    const int* __restrict__ x, const float* __restrict__ emb,
    double* __restrict__ xt, const int t0)
{
    const int b  = (int)blockIdx.x & 63;
    const int ti = (int)blockIdx.x >> 6;
    const int token = x[b * Sn + t0 + ti];
    const float* __restrict__ er = emb + (size_t)token * En;
    double* __restrict__ xo = xt + (size_t)ti * En * 64;
    for (int k = (int)threadIdx.x; k < En; k += 256)
        xo[(size_t)k * 64 + b] = (double)er[k];
}

// ---------- core GEMV helpers ----------
__device__ __forceinline__ void ldw4(const double* __restrict__ p,
                                     double& x, double& y, double& z, double& w) {
    const double4 v = *(const double4*)p; x = v.x; y = v.y; z = v.z; w = v.w;
}
__device__ __forceinline__ void ldw4(const float* __restrict__ p,
                                     double& x, double& y, double& z, double& w) {
    const float4 v = *(const float4*)p;
    x = (double)v.x; y = (double)v.y; z = (double)v.z; w = (double)v.w;
}

// 4-row x K dot-product block: state xp is [k][64] (lane offset pre-applied),
// weight rows r0..r3 are contiguous-K. C = K chunk length (compile-time).
template<typename WT, int C>
__device__ __forceinline__ void gemv4(
    const WT* __restrict__ r0, const WT* __restrict__ r1,
    const WT* __restrict__ r2, const WT* __restrict__ r3,
    const double* __restrict__ xp,
    double& a0, double& a1, double& a2, double& a3)
{
    #pragma unroll 2
    for (int i = 0; i < C / 4; ++i) {
        const size_t kk = (size_t)(4 * i) * 64;
        const double x0 = xp[kk], x1 = xp[kk + 64], x2 = xp[kk + 128], x3 = xp[kk + 192];
        double wx, wy, wz, ww;
        ldw4(r0 + 4 * i, wx, wy, wz, ww);
        a0 = fma(x0, wx, a0); a0 = fma(x1, wy, a0); a0 = fma(x2, wz, a0); a0 = fma(x3, ww, a0);
        ldw4(r1 + 4 * i, wx, wy, wz, ww);
        a1 = fma(x0, wx, a1); a1 = fma(x1, wy, a1); a1 = fma(x2, wz, a1); a1 = fma(x3, ww, a1);
        ldw4(r2 + 4 * i, wx, wy, wz, ww);
        a2 = fma(x0, wx, a2); a2 = fma(x1, wy, a2); a2 = fma(x2, wz, a2); a2 = fma(x3, ww, a2);
        ldw4(r3 + 4 * i, wx, wy, wz, ww);
        a3 = fma(x0, wx, a3); a3 = fma(x1, wy, a3); a3 = fma(x2, wz, a3); a3 = fma(x3, ww, a3);
    }
}

// ---------- LSTM cell: block = 512 thr = 8 waves; covers 4 j x 4 gates x 64 b.
// wave w: gate g = w&3, K-half = w>>2; 4 j-rows per wave (4 f64 accumulators/lane).
// Partials reduced in LDS; nonlinearity fused in epilogue. Grid = Hn/4 = 256.
template<typename WT, int KX>
__global__ __launch_bounds__(512) void cell_gemm(
    const double* __restrict__ xt,    // [KX][64]
    const double* __restrict__ hin,   // [Hn][64]
    double*       __restrict__ hout,  // [Hn][64]
    double*       __restrict__ cst,   // [Hn][64]
    const WT*     __restrict__ Wih,   // [4Hn][KX] rows i,f,g,o
    const WT*     __restrict__ Whh,   // [4Hn][Hn]
    const double* __restrict__ bc)    // [4Hn] = bih+bhh (f64)
{
    __shared__ double part[2][4][4][64];   // [half][gate][j_local][b]
    const int tid  = (int)threadIdx.x;
    const int b    = tid & 63;
    const int w    = tid >> 6;
    const int g    = w & 3;
    const int half = w >> 2;
    const int jt   = (int)blockIdx.x;      // j-tile: j = jt*4 + 0..3

    double a0 = 0.0, a1 = 0.0, a2 = 0.0, a3 = 0.0;

    {   // x-part
        constexpr int C = KX / 2;
        const int k0 = half * C;
        const size_t rb = ((size_t)g * Hn + (size_t)jt * 4) * KX + k0;
        gemv4<WT, C>(Wih + rb, Wih + rb + KX, Wih + rb + 2 * KX, Wih + rb + 3 * KX,
                     xt + (size_t)k0 * 64 + b, a0, a1, a2, a3);
    }
    {   // h-part
        constexpr int C = Hn / 2;
        const int k0 = half * C;
        const size_t rb = ((size_t)g * Hn + (size_t)jt * 4) * Hn + k0;
        gemv4<WT, C>(Whh + rb, Whh + rb + Hn, Whh + rb + 2 * Hn, Whh + rb + 3 * Hn,
                     hin + (size_t)k0 * 64 + b, a0, a1, a2, a3);
    }

    part[half][g][0][b] = a0;
    part[half][g][1][b] = a1;
    part[half][g][2][b] = a2;
    part[half][g][3][b] = a3;
    __syncthreads();

    if (tid < 256) {
        const int jl = tid >> 6;
        const int bb = tid & 63;
        const int j  = jt * 4 + jl;
        const double ai = bc[0 * Hn + j] + part[0][0][jl][bb] + part[1][0][jl][bb];
        const double af = bc[1 * Hn + j] + part[0][1][jl][bb] + part[1][1][jl][bb];
        const double ag = bc[2 * Hn + j] + part[0][2][jl][bb] + part[1][2][jl][bb];
        const double ao = bc[3 * Hn + j] + part[0][3][jl][bb] + part[1][3][jl][bb];
        const double ig = sigd(ai);
        const double fg = sigd(af);
        const double gg = tanh(ag);
        const double og = sigd(ao);
        const size_t idx = (size_t)j * 64 + bb;
        const double cn = fg * cst[idx] + ig * gg;
        cst[idx] = cn;
        hout[idx] = og * tanh(cn);
    }
}

// ---------- logits: block = 256 thr = 4 waves, 4 v-rows per wave, full K.
// Grid = Vn/16 = 625. LDS transpose -> coalesced float4 stores.
template<typename WT>
__global__ __launch_bounds__(256) void logits_gemm(
    const double* __restrict__ h,     // [Hn][64]
    const WT*     __restrict__ Wfc,   // [Vn][Hn]
    const double* __restrict__ bfcd,  // [Vn] f64
    float*        __restrict__ outf)  // d_out + t*Vn ; b stride = Tn*Vn
{
    __shared__ double lt[16][64];
    const int tid = (int)threadIdx.x;
    const int b = tid & 63;
    const int w = tid >> 6;
    const int v0 = (int)blockIdx.x * 16;

    double a0 = 0.0, a1 = 0.0, a2 = 0.0, a3 = 0.0;
    const size_t rb = ((size_t)v0 + (size_t)w * 4) * Hn;
    gemv4<WT, Hn>(Wfc + rb, Wfc + rb + Hn, Wfc + rb + 2 * Hn, Wfc + rb + 3 * Hn,
                  h + b, a0, a1, a2, a3);

    lt[w * 4 + 0][b] = a0 + bfcd[v0 + w * 4 + 0];
    lt[w * 4 + 1][b] = a1 + bfcd[v0 + w * 4 + 1];
    lt[w * 4 + 2][b] = a2 + bfcd[v0 + w * 4 + 2];
    lt[w * 4 + 3][b] = a3 + bfcd[v0 + w * 4 + 3];
    __syncthreads();

    // store: thread t -> batch bb = t>>2, v chunk vl = (t&3)*4 ; float4 per thread
    const int bb = tid >> 2;
    const int vl = (tid & 3) * 4;
    float4 o;
    o.x = (float)lt[vl + 0][bb];
    o.y = (float)lt[vl + 1][bb];
    o.z = (float)lt[vl + 2][bb];
    o.w = (float)lt[vl + 3][bb];
    *(float4*)(outf + (size_t)bb * ((size_t)Tn * Vn) + v0 + vl) = o;
}

// ---------- fused argmax (first-index, jnp semantics) + embedding gather (f64 xt) ----------
template<typename T>
__global__ __launch_bounds__(256) void argmax_gather(
    const T* __restrict__ vals, const int n, const int estride, const size_t bstride,
    const float* __restrict__ emb, double* __restrict__ xt)
{
    __shared__ double sv[256];
    __shared__ int si[256];
    __shared__ int stok;
    const int tid = (int)threadIdx.x;
    const int b = (int)blockIdx.x;
    const T* __restrict__ row = vals + (size_t)b * bstride;
    double best = -DBL_MAX;
    int bi = 0x7fffffff;
    for (int k = tid; k < n; k += 256) {
        const double v = (double)row[(size_t)k * estride];
        if (v > best) { best = v; bi = k; }
    }
    sv[tid] = best; si[tid] = bi;
    __syncthreads();
    for (int s = 128; s > 0; s >>= 1) {
        if (tid < s) {
            if (sv[tid + s] > sv[tid] || (sv[tid + s] == sv[tid] && si[tid + s] < si[tid])) {
                sv[tid] = sv[tid + s];
                si[tid] = si[tid + s];
            }
        }
        __syncthreads();
    }
    if (tid == 0) stok = si[0];
    __syncthreads();
    const float* __restrict__ er = emb + (size_t)stok * En;
    for (int k = tid; k < En; k += 256)
        xt[(size_t)k * 64 + b] = (double)er[k];
}

// ---------- templated pipeline (WT = double when ws holds f64 weights, else float) ----------
template<typename WT>
void run_pipeline(const int* x, const float* emb,
                  const WT* Wih0, const WT* Whh0, const WT* Wih1, const WT* Whh1,
                  const WT* Wfc,
                  double* ws, float* out, hipStream_t stream)
{
    double* h0s[2] = { ws + OFF_H0A, ws + OFF_H0B };
    double* h1s[2] = { ws + OFF_H1A, ws + OFF_H1B };
    double* c0 = ws + OFF_C0;
    double* c1 = ws + OFF_C1;
    double* xt = ws + OFF_XT;
    const double* bc0  = ws + OFF_BC0;
    const double* bc1  = ws + OFF_BC1;
    const double* bfcd = ws + OFF_BFC;

    int p = 0;
    for (int t0 = 0; t0 < Sn; t0 += ENC_CHUNK) {
        gather_enc<<<ENC_CHUNK * 64, 256, 0, stream>>>(x, emb, xt, t0);
        for (int ti = 0; ti < ENC_CHUNK; ++ti) {
            cell_gemm<WT, En><<<Hn / 4, 512, 0, stream>>>(
                xt + (size_t)ti * En * 64, h0s[p], h0s[1 - p], c0, Wih0, Whh0, bc0);
            cell_gemm<WT, Hn><<<Hn / 4, 512, 0, stream>>>(
                h0s[1 - p], h1s[p], h1s[1 - p], c1, Wih1, Whh1, bc1);
            p ^= 1;
        }
    }

    logits_gemm<WT><<<Vn / 16, 256, 0, stream>>>(h1s[p], Wfc, bfcd, out);
    argmax_gather<double><<<64, 256, 0, stream>>>(h1s[p], Hn, 64, 1, emb, xt);

    for (int s = 0; s < DEC; ++s) {
        cell_gemm<WT, En><<<Hn / 4, 512, 0, stream>>>(
            xt, h0s[p], h0s[1 - p], c0, Wih0, Whh0, bc0);
        cell_gemm<WT, Hn><<<Hn / 4, 512, 0, stream>>>(
            h0s[1 - p], h1s[p], h1s[1 - p], c1, Wih1, Whh1, bc1);
        p ^= 1;
        logits_gemm<WT><<<Vn / 16, 256, 0, stream>>>(
            h1s[p], Wfc, bfcd, out + (size_t)(1 + s) * Vn);
        if (s + 1 < DEC) {
            argmax_gather<float><<<64, 256, 0, stream>>>(
                out + (size_t)(1 + s) * Vn, Vn, 1, (size_t)Tn * Vn, emb, xt);
        }
    }
}

} // namespace

extern "C" void kernel_launch(void* const* d_in, const int* in_sizes, int n_in,
                              void* d_out, int out_size, void* d_ws, size_t ws_size,
                              hipStream_t stream)
{
    const int*   x    = (const int*)d_in[0];
    const float* emb  = (const float*)d_in[1];
    const float* Wih0 = (const float*)d_in[2];
    const float* Whh0 = (const float*)d_in[3];
    const float* bih0 = (const float*)d_in[4];
    const float* bhh0 = (const float*)d_in[5];
    const float* Wih1 = (const float*)d_in[6];
    const float* Whh1 = (const float*)d_in[7];
    const float* bih1 = (const float*)d_in[8];
    const float* bhh1 = (const float*)d_in[9];
    const float* Wfc  = (const float*)d_in[10];
    const float* bfc  = (const float*)d_in[11];
    float* out = (float*)d_out;
    double* ws = (double*)d_ws;

    init_state<<<1536, 256, 0, stream>>>(ws);   // zero h0 A/B, c0, h1 A/B, c1

    // biases always prepped to f64 in ws (tiny)
    bias_combine<<<16, 256, 0, stream>>>(bih0, bhh0, ws + OFF_BC0, 4 * Hn);
    bias_combine<<<16, 256, 0, stream>>>(bih1, bhh1, ws + OFF_BC1, 4 * Hn);
    cvt_f32_f64<<<40, 256, 0, stream>>>(bfc, ws + OFF_BFC, Vn);

    const bool wf64 = ws_size >= WS_NEED * sizeof(double);
    if (wf64) {
        cvt_f32_f64<<<4096, 256, 0, stream>>>(Wih0, ws + OFF_WIH0, (int)N_WIH0);
        cvt_f32_f64<<<4096, 256, 0, stream>>>(Whh0, ws + OFF_WHH0, (int)N_WHH);
        cvt_f32_f64<<<4096, 256, 0, stream>>>(Wih1, ws + OFF_WIH1, (int)N_WHH);
        cvt_f32_f64<<<4096, 256, 0, stream>>>(Whh1, ws + OFF_WHH1, (int)N_WHH);
        cvt_f32_f64<<<4096, 256, 0, stream>>>(Wfc,  ws + OFF_WFC,  (int)N_WFC);
        run_pipeline<double>(x, emb,
                             ws + OFF_WIH0, ws + OFF_WHH0, ws + OFF_WIH1, ws + OFF_WHH1,
                             ws + OFF_WFC, ws, out, stream);
    } else {
        run_pipeline<float>(x, emb, Wih0, Whh0, Wih1, Whh1, Wfc, ws, out, stream);
    }

    (void)in_sizes; (void)n_in; (void)out_size;
}